// Round 6
// baseline (378.114 us; speedup 1.0000x reference)
//
#include <hip/hip_runtime.h>

#define BB 8
#define NN 2048
#define FF 128
#define NBLK 512
#define RPB 32      // rows per block
#define RPW 8       // rows per wave
typedef unsigned long long ull;

// ws float layout:
//   [0,64)         barrier counters: bar[0], bar[32] (memset 256 B each launch)
//   [64,65600)     xpart (NBLK*FF)
//   [65600,66624)  S (BB*FF)
//   [66624,83008)  p (BB*NN)
//   [83008,99392)  r (BB*NN)

__global__ __launch_bounds__(256, 2) void fused_gat(
    const float* __restrict__ X, const float* __restrict__ A,
    const float* __restrict__ W, const float* __restrict__ av,
    const float* __restrict__ bias_W, float* __restrict__ Hout,
    unsigned* __restrict__ bar, float* __restrict__ xpart,
    float* __restrict__ S, float* __restrict__ p, float* __restrict__ r)
{
    __shared__ float lds[NN];                   // p then r staging (8 KB)
    __shared__ float wls[FF], xls[FF], sls[FF], bwls[FF];

    const int t = threadIdx.x;
    const int lane = t & 63;
    const int wave = t >> 6;
    const int blk = blockIdx.x;
    const int row0 = blk * RPB;                 // global row base
    const int b = row0 >> 11;                   // batch

    // ---------------- phase 1: w_ai, p (own 32 rows), xpart ----------------
    if (t < FF) {
        float s = 0.f;
#pragma unroll 8
        for (int f = 0; f < FF; ++f) s += W[t * FF + f] * av[FF + f];
        wls[t] = s;
        xls[t] = 0.f;
    }
    __syncthreads();
    {
        const int hf = lane >> 5, l32 = lane & 31;
        const float4 wv = ((const float4*)wls)[l32];
        float4 cs = make_float4(0.f, 0.f, 0.f, 0.f);
        const float4* X4 = (const float4*)(X + (size_t)row0 * FF);
#pragma unroll
        for (int k = 0; k < 4; ++k) {
            const int rloc = k * 8 + wave * 2 + hf;
            const float4 xv = X4[(size_t)rloc * 32 + l32];
            cs.x += xv.x; cs.y += xv.y; cs.z += xv.z; cs.w += xv.w;
            float s = xv.x * wv.x + xv.y * wv.y + xv.z * wv.z + xv.w * wv.w;
#pragma unroll
            for (int off = 16; off; off >>= 1) s += __shfl_xor(s, off, 64);
            if (l32 == 0) p[row0 + rloc] = expf(s);
        }
        atomicAdd(&xls[l32 * 4 + 0], cs.x);
        atomicAdd(&xls[l32 * 4 + 1], cs.y);
        atomicAdd(&xls[l32 * 4 + 2], cs.z);
        atomicAdd(&xls[l32 * 4 + 3], cs.w);
    }
    __syncthreads();
    if (t < FF) xpart[blk * FF + t] = xls[t];
    __threadfence();                              // publish p + xpart
    __syncthreads();
    if (t == 0)
        __hip_atomic_fetch_add(&bar[0], 1u, __ATOMIC_RELEASE, __HIP_MEMORY_SCOPE_AGENT);

    // -------- phase 2: stream own 8 A-rows per wave, bits stay in-lane --------
    // bit (it*4+c) of bits[q] = (A[rA+q][it*256 + lane*4 + c] != 0)
    unsigned bits[8] = {0, 0, 0, 0, 0, 0, 0, 0};
    const int rA = row0 + wave * RPW;
    {
        const float* Abase = A + (size_t)rA * NN;
#pragma unroll 2
        for (int it = 0; it < 8; ++it) {
#pragma unroll
            for (int q = 0; q < 8; ++q) {
                const float4 v = ((const float4*)(Abase + (size_t)q * NN))[it * 64 + lane];
                unsigned nib = 0;
                if (v.x != 0.f) nib |= 1u;
                if (v.y != 0.f) nib |= 2u;
                if (v.z != 0.f) nib |= 4u;
                if (v.w != 0.f) nib |= 8u;
                bits[q] |= nib << (it * 4);
            }
        }
    }

    // barrier 0 wait (p ready device-wide; counter is full by now — A-stream took far longer)
    if (t == 0) {
        while (__hip_atomic_load(&bar[0], __ATOMIC_ACQUIRE, __HIP_MEMORY_SCOPE_AGENT) < NBLK)
            __builtin_amdgcn_s_sleep(1);
    }
    __syncthreads();

    // -------- phase 2b: stage p[b,:], dot bits . p, write r --------
    float4* l4 = (float4*)lds;
    {
        const float4* pg = (const float4*)(p + (size_t)b * NN);
        l4[t]       = pg[t];
        l4[t + 256] = pg[t + 256];
    }
    __syncthreads();
    {
        float acc[8] = {0, 0, 0, 0, 0, 0, 0, 0};
#pragma unroll
        for (int it = 0; it < 8; ++it) {
            const float4 pv = l4[it * 64 + lane];
#pragma unroll
            for (int q = 0; q < 8; ++q) {
                const unsigned nib = (bits[q] >> (it * 4)) & 15u;
                acc[q] += (nib & 1u) ? pv.x : 0.f;
                acc[q] += (nib & 2u) ? pv.y : 0.f;
                acc[q] += (nib & 4u) ? pv.z : 0.f;
                acc[q] += (nib & 8u) ? pv.w : 0.f;
            }
        }
#pragma unroll
        for (int q = 0; q < 8; ++q)
#pragma unroll
            for (int off = 32; off; off >>= 1) acc[q] += __shfl_xor(acc[q], off, 64);
        if (lane == 0) {
            const int lr = rA & (NN - 1);
#pragma unroll
            for (int q = 0; q < 8; ++q)
                r[rA + q] = (acc[q] != 0.f) ? (lds[lr + q] / acc[q]) : 0.f;
        }
    }

    // designated blocks (one per batch): xsum reduce + S = xsum . W
    if ((blk & 63) == 0) {
        __syncthreads();
        if (t < FF) {
            const float* xp = xpart + (size_t)(b * 64) * FF + t;
            float s = 0.f;
#pragma unroll 4
            for (int j = 0; j < 64; ++j) s += xp[j * FF];
            xls[t] = s;
        }
        __syncthreads();
        if (t < FF) {
            float s = 0.f;
#pragma unroll 8
            for (int c2 = 0; c2 < FF; ++c2) s += xls[c2] * W[c2 * FF + t];
            S[b * FF + t] = s;
        }
    }

    // barrier 1: publish r and S
    __threadfence();
    __syncthreads();
    if (t == 0) {
        __hip_atomic_fetch_add(&bar[32], 1u, __ATOMIC_RELEASE, __HIP_MEMORY_SCOPE_AGENT);
        while (__hip_atomic_load(&bar[32], __ATOMIC_ACQUIRE, __HIP_MEMORY_SCOPE_AGENT) < NBLK)
            __builtin_amdgcn_s_sleep(1);
    }
    __syncthreads();

    // -------- phase 3: stage r[b,:], S, bias; dot bits . r; write H --------
    {
        const float4* rg = (const float4*)(r + (size_t)b * NN);
        l4[t]       = rg[t];
        l4[t + 256] = rg[t + 256];
        if (t < FF) { sls[t] = S[(size_t)b * FF + t]; bwls[t] = bias_W[t]; }
    }
    __syncthreads();
    {
        float acc[8] = {0, 0, 0, 0, 0, 0, 0, 0};
#pragma unroll
        for (int it = 0; it < 8; ++it) {
            const float4 rv = l4[it * 64 + lane];
#pragma unroll
            for (int q = 0; q < 8; ++q) {
                const unsigned nib = (bits[q] >> (it * 4)) & 15u;
                acc[q] += (nib & 1u) ? rv.x : 0.f;
                acc[q] += (nib & 2u) ? rv.y : 0.f;
                acc[q] += (nib & 4u) ? rv.z : 0.f;
                acc[q] += (nib & 8u) ? rv.w : 0.f;
            }
        }
#pragma unroll
        for (int q = 0; q < 8; ++q)
#pragma unroll
            for (int off = 32; off; off >>= 1) acc[q] += __shfl_xor(acc[q], off, 64);

        const float2 sv = ((const float2*)sls)[lane];
        const float2 bv = ((const float2*)bwls)[lane];
        float2* H2 = (float2*)Hout;
#pragma unroll
        for (int q = 0; q < 8; ++q)
            H2[(size_t)(rA + q) * 64 + lane] =
                make_float2(acc[q] * sv.x + bv.x, acc[q] * sv.y + bv.y);
    }
}

extern "C" void kernel_launch(void* const* d_in, const int* in_sizes, int n_in,
                              void* d_out, int out_size, void* d_ws, size_t ws_size,
                              hipStream_t stream) {
    const float* X      = (const float*)d_in[0];
    const float* A      = (const float*)d_in[1];
    const float* W      = (const float*)d_in[2];
    const float* a      = (const float*)d_in[3];
    // d_in[4] = bias_a : algebraically cancels (rank-1 den), unused
    const float* bias_W = (const float*)d_in[5];
    float* out = (float*)d_out;

    float* ws = (float*)d_ws;
    unsigned* bar = (unsigned*)ws;        // [0,64) floats
    float* xpart = ws + 64;               // NBLK*FF = 65536
    float* S     = ws + 65600;            // BB*FF  = 1024
    float* p     = ws + 66624;            // BB*NN  = 16384
    float* r     = ws + 83008;            // BB*NN  = 16384

    hipMemsetAsync(bar, 0, 256, stream);
    fused_gat<<<NBLK, 256, 0, stream>>>(X, A, W, a, bias_W, out, bar, xpart, S, p, r);
}